// Round 2
// baseline (392.583 us; speedup 1.0000x reference)
//
#include <hip/hip_runtime.h>

#define HDIM   1024
#define BSZ    32
#define SLEN   2048
#define NCHUNK 128          // s-chunks per batch
#define CHUNK  16           // SLEN / NCHUNK, rows per wave
#define WPB    4            // waves per block

__device__ __forceinline__ float wave_reduce_sum(float v) {
    #pragma unroll
    for (int off = 32; off > 0; off >>= 1) v += __shfl_xor(v, off, 64);
    return v;
}

// K1: u2[j] = sum_e v[e] * W[e, H + j]  (only the We half matters: the Wh/bias
// part is a per-batch constant in the energies, which softmax cancels).
// grid (4, 32) x 256, atomicAdd accumulate.
__global__ __launch_bounds__(256) void k_vtw(const float* __restrict__ W,
                                             const float* __restrict__ v,
                                             float* __restrict__ u2) {
    const int j  = blockIdx.x * 256 + threadIdx.x;   // 0..1023
    const int e0 = blockIdx.y * 32;
    float acc = 0.f;
    #pragma unroll 8
    for (int e = 0; e < 32; ++e)
        acc += v[e0 + e] * W[(size_t)(e0 + e) * (2 * HDIM) + HDIM + j];
    atomicAdd(&u2[j], acc);
}

// K2: flash pass. One WAVE per (b, chunk of 16 rows). Row lives entirely in
// registers (4 float4/lane); no LDS, no __syncthreads. Online softmax with
// defer-max (THR=8) so the O-rescale is rare.
__global__ __launch_bounds__(256) void k_flash(const float* __restrict__ enc,
                                               const float* __restrict__ u2,
                                               float* __restrict__ e_out,
                                               float* __restrict__ m_out,
                                               float* __restrict__ z_out,
                                               float* __restrict__ o_out) {
    const int t    = threadIdx.x;
    const int lane = t & 63;
    const int gw   = blockIdx.x * WPB + (t >> 6);
    const int b    = gw >> 7;               // / NCHUNK
    const int ck   = gw & (NCHUNK - 1);

    const float4* __restrict__ u4 = reinterpret_cast<const float4*>(u2);
    float4 ur[4];
    #pragma unroll
    for (int s = 0; s < 4; ++s) ur[s] = u4[s * 64 + lane];

    const float4* __restrict__ base =
        reinterpret_cast<const float4*>(enc)
        + (size_t)(b * SLEN + ck * CHUNK) * (HDIM / 4);

    float m = -3.4e38f, z = 0.f;
    float4 o[4];
    #pragma unroll
    for (int s = 0; s < 4; ++s) o[s] = make_float4(0.f, 0.f, 0.f, 0.f);

    float4 buf[2][4];
    #pragma unroll
    for (int s = 0; s < 4; ++s) buf[0][s] = base[s * 64 + lane];

    #pragma unroll
    for (int r = 0; r < CHUNK; ++r) {
        const int cur = r & 1, nxt = cur ^ 1;
        if (r + 1 < CHUNK) {
            #pragma unroll
            for (int s = 0; s < 4; ++s)
                buf[nxt][s] = base[(size_t)(r + 1) * (HDIM / 4) + s * 64 + lane];
        }
        float d = 0.f;
        #pragma unroll
        for (int s = 0; s < 4; ++s)
            d += buf[cur][s].x * ur[s].x + buf[cur][s].y * ur[s].y
               + buf[cur][s].z * ur[s].z + buf[cur][s].w * ur[s].w;
        d = wave_reduce_sum(d);
        if (lane == 0) e_out[(size_t)b * SLEN + ck * CHUNK + r] = d;

        const float diff = d - m;
        if (diff <= 8.0f) {                 // wave-uniform branch
            const float p = __expf(diff);
            z += p;
            #pragma unroll
            for (int s = 0; s < 4; ++s) {
                o[s].x += p * buf[cur][s].x; o[s].y += p * buf[cur][s].y;
                o[s].z += p * buf[cur][s].z; o[s].w += p * buf[cur][s].w;
            }
        } else {                            // rescale (rare; 1st row hits this)
            const float rsc = __expf(m - d);  // exp(-huge) = 0 on 1st row
            z = z * rsc + 1.f;
            #pragma unroll
            for (int s = 0; s < 4; ++s) {
                o[s].x = o[s].x * rsc + buf[cur][s].x;
                o[s].y = o[s].y * rsc + buf[cur][s].y;
                o[s].z = o[s].z * rsc + buf[cur][s].z;
                o[s].w = o[s].w * rsc + buf[cur][s].w;
            }
            m = d;
        }
    }

    const int pidx = b * NCHUNK + ck;
    float4* op = reinterpret_cast<float4*>(o_out) + (size_t)pidx * (HDIM / 4);
    #pragma unroll
    for (int s = 0; s < 4; ++s) op[s * 64 + lane] = o[s];
    if (lane == 0) { m_out[pidx] = m; z_out[pidx] = z; }
}

// K3: combine partials. grid (B, 9): y<8 -> context col-group of 128 cols,
// y==8 -> attn_weights for the batch row.
__global__ __launch_bounds__(256) void k_combine(const float* __restrict__ e_in,
                                                 const float* __restrict__ m_in,
                                                 const float* __restrict__ z_in,
                                                 const float* __restrict__ o_in,
                                                 float* __restrict__ out) {
    const int t    = threadIdx.x;
    const int b    = blockIdx.x;
    const int part = blockIdx.y;

    __shared__ float sm[NCHUNK];
    __shared__ float sscale[NCHUNK];
    __shared__ float red[256];

    if (t < NCHUNK) sm[t] = m_in[b * NCHUNK + t];
    __syncthreads();
    red[t] = (t < NCHUNK) ? sm[t] : -3.4e38f;
    __syncthreads();
    #pragma unroll
    for (int s = 128; s > 0; s >>= 1) {
        if (t < s) red[t] = fmaxf(red[t], red[t + s]);
        __syncthreads();
    }
    const float M = red[0];
    __syncthreads();
    float lz = 0.f;
    if (t < NCHUNK) {
        const float sc = __expf(sm[t] - M);
        sscale[t] = sc;
        lz = sc * z_in[b * NCHUNK + t];
    }
    red[t] = lz;
    __syncthreads();
    #pragma unroll
    for (int s = 128; s > 0; s >>= 1) {
        if (t < s) red[t] += red[t + s];
        __syncthreads();
    }
    const float Z    = red[0];
    const float invZ = 1.0f / Z;
    __syncthreads();

    if (part < 8) {
        // context cols [part*128, part*128+128): 32 float4s.
        const int j  = t & 31;     // float4 index within group
        const int c0 = t >> 5;     // 0..7
        float4 acc = make_float4(0.f, 0.f, 0.f, 0.f);
        for (int c = c0; c < NCHUNK; c += 8) {
            const float sc  = sscale[c];
            const float4 o4 = reinterpret_cast<const float4*>(o_in)
                [(size_t)(b * NCHUNK + c) * (HDIM / 4) + part * 32 + j];
            acc.x += sc * o4.x; acc.y += sc * o4.y;
            acc.z += sc * o4.z; acc.w += sc * o4.w;
        }
        __shared__ float4 r4[256];
        r4[t] = acc;
        __syncthreads();
        if (t < 32) {
            float4 s4 = r4[t];
            #pragma unroll
            for (int g = 1; g < 8; ++g) {
                const float4 oo = r4[g * 32 + t];
                s4.x += oo.x; s4.y += oo.y; s4.z += oo.z; s4.w += oo.w;
            }
            s4.x *= invZ; s4.y *= invZ; s4.z *= invZ; s4.w *= invZ;
            *reinterpret_cast<float4*>(out + (size_t)b * HDIM
                                       + part * 128 + t * 4) = s4;
        }
    } else {
        // attn_weights[b, :] = exp(e - M) / Z
        const float* ein  = e_in + (size_t)b * SLEN;
        float*       wout = out + (size_t)BSZ * HDIM + (size_t)b * SLEN;
        for (int i = t; i < SLEN / 4; i += 256) {
            const float4 e4 = *reinterpret_cast<const float4*>(ein + i * 4);
            float4 w4;
            w4.x = __expf(e4.x - M) * invZ;
            w4.y = __expf(e4.y - M) * invZ;
            w4.z = __expf(e4.z - M) * invZ;
            w4.w = __expf(e4.w - M) * invZ;
            *reinterpret_cast<float4*>(wout + i * 4) = w4;
        }
    }
}

extern "C" void kernel_launch(void* const* d_in, const int* in_sizes, int n_in,
                              void* d_out, int out_size, void* d_ws, size_t ws_size,
                              hipStream_t stream) {
    (void)in_sizes; (void)n_in; (void)out_size; (void)ws_size;
    const float* enc = (const float*)d_in[1];   // (B,S,H)
    const float* W   = (const float*)d_in[2];   // (H,2H)
    const float* v   = (const float*)d_in[4];   // (H,1)
    float* out = (float*)d_out;

    float* u2   = (float*)d_ws;                      // H
    float* e_ws = u2 + HDIM;                         // B*S
    float* m_ws = e_ws + (size_t)BSZ * SLEN;         // B*NCHUNK
    float* z_ws = m_ws + BSZ * NCHUNK;               // B*NCHUNK
    float* o_ws = z_ws + BSZ * NCHUNK;               // B*NCHUNK*H

    hipMemsetAsync(u2, 0, HDIM * sizeof(float), stream);
    dim3 g1(4, 32);
    k_vtw<<<g1, 256, 0, stream>>>(W, v, u2);
    dim3 g2((BSZ * NCHUNK) / WPB);
    k_flash<<<g2, 256, 0, stream>>>(enc, u2, e_ws, m_ws, z_ws, o_ws);
    dim3 g3(BSZ, 9);
    k_combine<<<g3, 256, 0, stream>>>(e_ws, m_ws, z_ws, o_ws, out);
}